// Round 10
// baseline (143.685 us; speedup 1.0000x reference)
//
#include <hip/hip_runtime.h>

// MGN_NET: 3x NNConv(mean) + ReLU, then pairwise-L1 CBT [35x35]. All fp32.
// ROUND-6 CONFIG (best measured: 140.0 us) — reverted after R7/R8/R9 probes.
// 6 dispatches: prep(zero+lin2T) -> msg1 -> msg2(+x1 recompute) ->
//               msg3(+x2 slice recompute, +35 x2-writer blocks) -> x3 -> cbt
// Lessons (measured):
//  - R7: cooperative grid.sync ~35us each on gfx950 (global-atomic spin
//    across 8 XCDs) — never for ~30us of work.
//  - R4/R8: single-CU or 35x-redundant latency-bound recompute fusions lose
//    20-60us to save a ~3.5us dispatch boundary.
//  - R9: moving lin2T transpose into msg1's dispatch: neutral/slightly worse.
//  - Timed total is dominated by harness ws re-poison (268MB fill @ ~6.6TB/s
//    = ~40us) + replay overhead; kernel-sum ~30us.
// ws layout (floats): agg1@0[8960], agg2@8960[8960], agg3@17920[2240],
//   cnt@20160[35] (zero span 20195), lin2T@20224[65536], x2m@85760[8960],
//   x3@94720[2240]

#define NN 35
#define NE 1190
#define TE 10   // edges per edge-group; 1190 = 119*10
#define NG 119
#define NU2 476 // msg2/msg3 msg units: 119 eg x 4 og/ig

#define OFF_AGG1 0
#define OFF_AGG2 8960
#define OFF_AGG3 17920
#define OFF_CNT  20160
#define ZERO_N   20195
#define OFF_L2T  20224
#define OFF_X2M  85760
#define OFF_X3   94720

// prep: blocks 0..79 zero agg1/agg2/agg3/cnt; blocks 80..335 repack
// lin2T[i][o] = lin2[o][i] (coalesced writes; gathered reads are tiny).
__global__ __launch_bounds__(256) void prep_k(float* __restrict__ ws,
                                              const float* __restrict__ lin2) {
    int b = blockIdx.x, t = threadIdx.x;
    if (b < 80) {
        int idx = b * 256 + t;
        if (idx < ZERO_N) ws[idx] = 0.f;
    } else {
        int i = b - 80;
        ws[OFF_L2T + i * 256 + t] = lin2[t * 256 + i];
    }
}

// Layer 1: c_in=1, c_out=256. 2 edges/block x 256 o.
__global__ __launch_bounds__(512) void msg1_k(
    const float* __restrict__ x, const float* __restrict__ ea,
    const int* __restrict__ ei, const float* __restrict__ w1,
    const float* __restrict__ b1w, float* __restrict__ agg1,
    float* __restrict__ cnt) {
    int tid = threadIdx.x;
    int e = blockIdx.x * 2 + (tid >> 8);
    int o = tid & 255;
    int src = ei[e];
    int dst = ei[NE + e];
    float xs = x[src];
    const float* eap = ea + e * 6;
    const float* w = w1 + o * 6;
    float d = b1w[o];
#pragma unroll
    for (int v = 0; v < 6; v++) d = fmaf(eap[v], w[v], d);
    atomicAdd(agg1 + dst * 256 + o, xs * fmaxf(d, 0.f));
    if (o == 0) atomicAdd(cnt + dst, 1.0f);
}

// Layer 2 (+x1 recompute): grid 119 eg x 4 og; block 512 = 64 ol x 8 ic.
__global__ __launch_bounds__(512, 4) void msg2x1_k(
    const float* __restrict__ x, const float* __restrict__ ea,
    const int* __restrict__ ei, const float* __restrict__ lin1,
    const float* __restrict__ b1, const float* __restrict__ agg1,
    const float* __restrict__ cnt, const float* __restrict__ w2,
    const float* __restrict__ b2w, float* __restrict__ agg2) {
    __shared__ float xs[TE][256];
    __shared__ float eas[TE][6];
    __shared__ int srcs[TE], dsts[TE];
    __shared__ float part[7][TE][64];
    int tid = threadIdx.x;
    int eg = blockIdx.x >> 2, og = blockIdx.x & 3;
    int e0 = eg * TE;
    if (tid < TE) { srcs[tid] = ei[e0 + tid]; dsts[tid] = ei[NE + e0 + tid]; }
    if (tid >= 64 && tid < 64 + TE * 6) {
        int t = tid - 64;
        eas[t / 6][t % 6] = ea[e0 * 6 + t];
    }
    __syncthreads();
    for (int idx = tid; idx < TE * 256; idx += 512) {
        int te = idx >> 8, i = idx & 255;
        int s = srcs[te];
        float c = fmaxf(cnt[s], 1.f);
        float v = agg1[s * 256 + i] / c + x[s] * lin1[i] + b1[i];
        xs[te][i] = fmaxf(v, 0.f);
    }
    __syncthreads();
    int ol = tid & 63;
    int o = og * 64 + ol;
    int ic = tid >> 6;
    float eareg[TE][6];
#pragma unroll
    for (int te = 0; te < TE; te++)
#pragma unroll
        for (int v = 0; v < 6; v++) eareg[te][v] = eas[te][v];
    float acc[TE] = {};
    for (int ii = 0; ii < 32; ii++) {
        int i = ic * 32 + ii;
        const float* w = w2 + (size_t)(i * 256 + o) * 6;
        float2 wa = *(const float2*)w;
        float2 wb = *(const float2*)(w + 2);
        float2 wc = *(const float2*)(w + 4);
        float b = b2w[i * 256 + o];
#pragma unroll
        for (int te = 0; te < TE; te += 2) {
            float dx = b, dy = b;
            dx = fmaf(eareg[te][0], wa.x, dx); dy = fmaf(eareg[te + 1][0], wa.x, dy);
            dx = fmaf(eareg[te][1], wa.y, dx); dy = fmaf(eareg[te + 1][1], wa.y, dy);
            dx = fmaf(eareg[te][2], wb.x, dx); dy = fmaf(eareg[te + 1][2], wb.x, dy);
            dx = fmaf(eareg[te][3], wb.y, dx); dy = fmaf(eareg[te + 1][3], wb.y, dy);
            dx = fmaf(eareg[te][4], wc.x, dx); dy = fmaf(eareg[te + 1][4], wc.x, dy);
            dx = fmaf(eareg[te][5], wc.y, dx); dy = fmaf(eareg[te + 1][5], wc.y, dy);
            dx = fmaxf(dx, 0.f);               dy = fmaxf(dy, 0.f);
            acc[te] = fmaf(xs[te][i], dx, acc[te]);
            acc[te + 1] = fmaf(xs[te + 1][i], dy, acc[te + 1]);
        }
    }
    if (ic > 0) {
#pragma unroll
        for (int te = 0; te < TE; te++) part[ic - 1][te][ol] = acc[te];
    }
    __syncthreads();
    if (ic == 0) {
#pragma unroll
        for (int te = 0; te < TE; te++) {
            float s = acc[te];
#pragma unroll
            for (int p = 0; p < 7; p++) s += part[p][te][ol];
            atomicAdd(agg2 + dsts[te] * 256 + o, s);
        }
    }
}

// Layer 3 (+x2 slice via lin2T): blocks 0..475 msg units; 476..510 x2m writers.
__global__ __launch_bounds__(512, 4) void msg3x2_k(
    const float* __restrict__ x, const float* __restrict__ ea,
    const int* __restrict__ ei, const float* __restrict__ lin1,
    const float* __restrict__ b1, const float* __restrict__ agg1,
    const float* __restrict__ cnt, const float* __restrict__ lin2T,
    const float* __restrict__ b2, const float* __restrict__ agg2,
    const float* __restrict__ w3, const float* __restrict__ b3w,
    float* __restrict__ agg3, float* __restrict__ x2m) {
    __shared__ float x1r[TE][256];
    __shared__ float xs[TE][64];
    __shared__ float eas[TE][6];
    __shared__ int srcs[TE], dsts[TE];
    __shared__ float part[7][TE][64];
    int tid = threadIdx.x;

    if (blockIdx.x >= NU2) {
        int n = blockIdx.x - NU2;
        float c = fmaxf(cnt[n], 1.f);
        if (tid < 256) {
            float v = agg1[n * 256 + tid] / c + x[n] * lin1[tid] + b1[tid];
            x1r[0][tid] = fmaxf(v, 0.f);
        }
        __syncthreads();
        int o = tid & 255, ic = tid >> 8;
        float s = 0.f;
        for (int ii = 0; ii < 128; ii++) {
            int i = ic * 128 + ii;
            s = fmaf(lin2T[i * 256 + o], x1r[0][i], s);
        }
        float* p2 = &part[0][0][0];
        if (ic == 1) p2[o] = s;
        __syncthreads();
        if (ic == 0) {
            float v = agg2[n * 256 + o] / c + s + p2[o] + b2[o];
            x2m[n * 256 + o] = fmaxf(v, 0.f);
        }
        return;
    }

    int eg = blockIdx.x >> 2, ig = blockIdx.x & 3;
    int e0 = eg * TE;
    if (tid < TE) { srcs[tid] = ei[e0 + tid]; dsts[tid] = ei[NE + e0 + tid]; }
    if (tid >= 64 && tid < 64 + TE * 6) {
        int t = tid - 64;
        eas[t / 6][t % 6] = ea[e0 * 6 + t];
    }
    __syncthreads();
    for (int idx = tid; idx < TE * 256; idx += 512) {
        int te = idx >> 8, i = idx & 255;
        int s = srcs[te];
        float c = fmaxf(cnt[s], 1.f);
        float v = agg1[s * 256 + i] / c + x[s] * lin1[i] + b1[i];
        x1r[te][i] = fmaxf(v, 0.f);
    }
    __syncthreads();
    int ol = tid & 63;
    int ic = tid >> 6;
    int o2 = ig * 64 + ol;
    {
        float acc2[TE] = {};
        for (int ii = 0; ii < 32; ii++) {
            int i = ic * 32 + ii;
            float w = lin2T[i * 256 + o2];
#pragma unroll
            for (int te = 0; te < TE; te++)
                acc2[te] = fmaf(w, x1r[te][i], acc2[te]);
        }
        if (ic > 0) {
#pragma unroll
            for (int te = 0; te < TE; te++) part[ic - 1][te][ol] = acc2[te];
        }
        __syncthreads();
        if (ic == 0) {
#pragma unroll
            for (int te = 0; te < TE; te++) {
                float ssum = acc2[te];
#pragma unroll
                for (int p = 0; p < 7; p++) ssum += part[p][te][ol];
                int s = srcs[te];
                float c = fmaxf(cnt[s], 1.f);
                float v = agg2[s * 256 + o2] / c + ssum + b2[o2];
                xs[te][ol] = fmaxf(v, 0.f);
            }
        }
        __syncthreads();
    }
    float eareg[TE][6];
#pragma unroll
    for (int te = 0; te < TE; te++)
#pragma unroll
        for (int v = 0; v < 6; v++) eareg[te][v] = eas[te][v];
    float acc[TE] = {};
    for (int jj = 0; jj < 8; jj++) {
        int ii = ic * 8 + jj;
        int i = ig * 64 + ii;
        const float* w = w3 + (size_t)(i * 64 + ol) * 6;
        float2 wa = *(const float2*)w;
        float2 wb = *(const float2*)(w + 2);
        float2 wc = *(const float2*)(w + 4);
        float b = b3w[i * 64 + ol];
#pragma unroll
        for (int te = 0; te < TE; te += 2) {
            float dx = b, dy = b;
            dx = fmaf(eareg[te][0], wa.x, dx); dy = fmaf(eareg[te + 1][0], wa.x, dy);
            dx = fmaf(eareg[te][1], wa.y, dx); dy = fmaf(eareg[te + 1][1], wa.y, dy);
            dx = fmaf(eareg[te][2], wb.x, dx); dy = fmaf(eareg[te + 1][2], wb.x, dy);
            dx = fmaf(eareg[te][3], wb.y, dx); dy = fmaf(eareg[te + 1][3], wb.y, dy);
            dx = fmaf(eareg[te][4], wc.x, dx); dy = fmaf(eareg[te + 1][4], wc.x, dy);
            dx = fmaf(eareg[te][5], wc.y, dx); dy = fmaf(eareg[te + 1][5], wc.y, dy);
            dx = fmaxf(dx, 0.f);               dy = fmaxf(dy, 0.f);
            acc[te] = fmaf(xs[te][ii], dx, acc[te]);
            acc[te + 1] = fmaf(xs[te + 1][ii], dy, acc[te + 1]);
        }
    }
    if (ic > 0) {
#pragma unroll
        for (int te = 0; te < TE; te++) part[ic - 1][te][ol] = acc[te];
    }
    __syncthreads();
    if (ic == 0) {
#pragma unroll
        for (int te = 0; te < TE; te++) {
            float s = acc[te];
#pragma unroll
            for (int p = 0; p < 7; p++) s += part[p][te][ol];
            atomicAdd(agg3 + dsts[te] * 64 + ol, s);
        }
    }
}

// x3: 35 blocks x 256 thr (64 o x 4 i-chunks); per-lane lin3 row gather is
// fine at this block count (35 CUs' L1s in parallel).
__global__ __launch_bounds__(256) void x3_k(
    const float* __restrict__ x2m, const float* __restrict__ lin3,
    const float* __restrict__ b3, const float* __restrict__ agg3,
    const float* __restrict__ cnt, float* __restrict__ x3) {
    __shared__ float xr[256];
    __shared__ float part[3][64];
    int n = blockIdx.x, tid = threadIdx.x;
    int o = tid & 63, ic = tid >> 6;
    xr[tid] = x2m[n * 256 + tid];
    __syncthreads();
    const float4* w = (const float4*)(lin3 + (size_t)o * 256 + ic * 64);
    float s = 0.f;
#pragma unroll
    for (int k = 0; k < 16; k++) {
        float4 wv = w[k];
        int i = ic * 64 + k * 4;
        s = fmaf(wv.x, xr[i], s);
        s = fmaf(wv.y, xr[i + 1], s);
        s = fmaf(wv.z, xr[i + 2], s);
        s = fmaf(wv.w, xr[i + 3], s);
    }
    if (ic > 0) part[ic - 1][o] = s;
    __syncthreads();
    if (ic == 0) {
        float tot = s + part[0][o] + part[1][o] + part[2][o];
        float c = fmaxf(cnt[n], 1.f);
        x3[n * 64 + o] = fmaxf(agg3[n * 64 + o] / c + tot + b3[o], 0.f);
    }
}

__global__ __launch_bounds__(256) void cbt_k(const float* __restrict__ x3,
                                             float* __restrict__ out) {
    int t = blockIdx.x * 256 + threadIdx.x;
    if (t >= NN * NN) return;
    int i = t / NN, j = t % NN;
    const float* a = x3 + i * 64;
    const float* b = x3 + j * 64;
    float s = 0.f;
#pragma unroll
    for (int f = 0; f < 64; f++) s += fabsf(a[f] - b[f]);
    out[t] = s;
}

extern "C" void kernel_launch(void* const* d_in, const int* in_sizes, int n_in,
                              void* d_out, int out_size, void* d_ws, size_t ws_size,
                              hipStream_t stream) {
    const float* x    = (const float*)d_in[0];
    const float* ea   = (const float*)d_in[1];
    const int*   ei   = (const int*)d_in[2];
    const float* nn1w = (const float*)d_in[3];
    const float* nn1b = (const float*)d_in[4];
    const float* lin1 = (const float*)d_in[5];
    const float* b1   = (const float*)d_in[6];
    const float* nn2w = (const float*)d_in[7];
    const float* nn2b = (const float*)d_in[8];
    const float* lin2 = (const float*)d_in[9];
    const float* b2   = (const float*)d_in[10];
    const float* nn3w = (const float*)d_in[11];
    const float* nn3b = (const float*)d_in[12];
    const float* lin3 = (const float*)d_in[13];
    const float* b3   = (const float*)d_in[14];

    float* ws    = (float*)d_ws;
    float* agg1  = ws + OFF_AGG1;
    float* agg2  = ws + OFF_AGG2;
    float* agg3  = ws + OFF_AGG3;
    float* cnt   = ws + OFF_CNT;
    float* lin2T = ws + OFF_L2T;
    float* x2m   = ws + OFF_X2M;
    float* x3v   = ws + OFF_X3;
    float* out   = (float*)d_out;

    prep_k<<<336, 256, 0, stream>>>(ws, lin2);
    msg1_k<<<NE / 2, 512, 0, stream>>>(x, ea, ei, nn1w, nn1b, agg1, cnt);
    msg2x1_k<<<NG * 4, 512, 0, stream>>>(x, ea, ei, lin1, b1, agg1, cnt,
                                         nn2w, nn2b, agg2);
    msg3x2_k<<<NG * 4 + NN, 512, 0, stream>>>(x, ea, ei, lin1, b1, agg1, cnt,
                                              lin2T, b2, agg2, nn3w, nn3b,
                                              agg3, x2m);
    x3_k<<<NN, 256, 0, stream>>>(x2m, lin3, b3, agg3, cnt, x3v);
    cbt_k<<<(NN * NN + 255) / 256, 256, 0, stream>>>(x3v, out);
}